// Round 4
// baseline (3436.729 us; speedup 1.0000x reference)
//
#include <hip/hip_runtime.h>
#include <hip/hip_bf16.h>

// GCN 2-layer, N=50000, E=625000, feats 128->128->64. int32 edges.
// Input/output float dtype UNKNOWN (f32 per reference file vs bf16 per test
// label) -> runtime-detected flag; all kernels branch on it (wave-uniform).
// Workspace overlay (25.9 MB): flag @0, dinv f32[N] @256, row arena N x 512B:
//   phase1: z1 f32[128]           (bytes 0..512 of row)
//   gemm1 : h1 bf16[128] in-place (bytes 0..256)   -- rows wave-private
//   gemm2 : h2 bf16[64]  in-place (bytes 0..128)
//           agg2 f32[64]          (bytes 256..512)
// Layer1 aggregate-first (linearity), Layer2 GEMM-first.

typedef __attribute__((ext_vector_type(8))) __bf16 bf16x8;
typedef __attribute__((ext_vector_type(8))) unsigned short ushort8;
typedef __attribute__((ext_vector_type(4))) float floatx4;

static __device__ __forceinline__ float bf2f(unsigned short s) {
    unsigned u = ((unsigned)s) << 16;
    return __builtin_bit_cast(float, u);
}
static __device__ __forceinline__ unsigned short f2bf(float f) {
    unsigned u = __builtin_bit_cast(unsigned, f);
    unsigned r = (u + 0x7FFFu + ((u >> 16) & 1u)) >> 16;
    return (unsigned short)r;
}
// load 8 consecutive feature elements (idx in elements) as f32[8]
static __device__ __forceinline__ void ld8f(const void* p, size_t idx, int isbf, float* o) {
    if (isbf) {
        ushort8 t = __builtin_bit_cast(ushort8, *(const int4*)((const unsigned short*)p + idx));
        #pragma unroll
        for (int j = 0; j < 8; ++j) o[j] = bf2f(t[j]);
    } else {
        const float* f = (const float*)p + idx;
        float4 a = *(const float4*)f;
        float4 b = *(const float4*)(f + 4);
        o[0]=a.x; o[1]=a.y; o[2]=a.z; o[3]=a.w; o[4]=b.x; o[5]=b.y; o[6]=b.z; o[7]=b.w;
    }
}
// load 8 consecutive elements as a bf16x8 fragment
static __device__ __forceinline__ int4 ld8frag(const void* p, size_t idx, int isbf) {
    if (isbf) {
        return *(const int4*)((const unsigned short*)p + idx);
    } else {
        const float* f = (const float*)p + idx;
        float4 a = *(const float4*)f;
        float4 b = *(const float4*)(f + 4);
        ushort8 t;
        t[0]=f2bf(a.x); t[1]=f2bf(a.y); t[2]=f2bf(a.z); t[3]=f2bf(a.w);
        t[4]=f2bf(b.x); t[5]=f2bf(b.y); t[6]=f2bf(b.z); t[7]=f2bf(b.w);
        return __builtin_bit_cast(int4, t);
    }
}
static __device__ __forceinline__ float bread(const void* p, int i, int isbf) {
    return isbf ? bf2f(((const unsigned short*)p)[i]) : ((const float*)p)[i];
}

// ---------------- dtype detect: bf16 iff low halves of x words are sane bf16 ----
__global__ void k_detect(const unsigned* __restrict__ xw, int* flag) {
    __shared__ int red[256];
    int t = threadIdx.x;
    int cnt = 0;
    #pragma unroll
    for (int i = 0; i < 16; ++i) {
        unsigned w = xw[t * 16 + i];
        unsigned exp = (w >> 7) & 0xFFu;     // exponent of low-half bf16
        cnt += (exp <= 0x84u) ? 1 : 0;       // |v| < 64
    }
    red[t] = cnt;
    __syncthreads();
    for (int s = 128; s > 0; s >>= 1) {
        if (t < s) red[t] += red[t + s];
        __syncthreads();
    }
    if (t == 0) flag[0] = (red[0] >= 3686) ? 1 : 0;   // >=90% of 4096
}

// ---------------- degree / dinv ----------------
__global__ void k_fill1(float* deg, int n) {
    int i = blockIdx.x * 256 + threadIdx.x;
    if (i < n) deg[i] = 1.0f;   // self-loop
}
__global__ void k_deg(const int* __restrict__ dst, float* __restrict__ deg, int E) {
    int e = blockIdx.x * 256 + threadIdx.x;
    if (e < E) atomicAdd(&deg[dst[e]], 1.0f);
}
__global__ void k_rsqrt(float* deg, int n) {
    int i = blockIdx.x * 256 + threadIdx.x;
    if (i < n) deg[i] = rsqrtf(deg[i]);
}

// ---------------- z1 init: buf[i,:] = dinv[i]^2 * x[i,:] ----------------
__global__ __launch_bounds__(256) void k_selfx(
    const void* __restrict__ x, const float* __restrict__ dinv,
    float* buf, int N, const int* __restrict__ flag)
{
    int isbf = *flag;
    int idx = blockIdx.x * 256 + threadIdx.x;       // N*16 threads
    if (idx >= N * 16) return;
    int i = idx >> 4, c8 = idx & 15;
    float w = dinv[i]; w = w * w;
    float v[8];
    ld8f(x, (size_t)i * 128 + c8 * 8, isbf, v);
    float* out = &buf[i * 128 + c8 * 8];
    #pragma unroll
    for (int j = 0; j < 8; ++j) out[j] = w * v[j];
}

// ---------------- edge agg layer1: buf[d,:] += w * x[s,:] (128 f32) ------------
__global__ __launch_bounds__(256) void k_aggx(
    const int* __restrict__ src, const int* __restrict__ dst,
    const float* __restrict__ dinv, const void* __restrict__ x,
    float* buf, int E, const int* __restrict__ flag)
{
    int isbf = *flag;
    int gid = blockIdx.x * 256 + threadIdx.x;
    int e = gid >> 4, p = gid & 15;
    if (e >= E) return;
    int s = src[e], d = dst[e];
    float w = dinv[s] * dinv[d];
    float v[8];
    ld8f(x, (size_t)s * 128 + p * 8, isbf, v);
    float* out = &buf[d * 128 + p * 8];
    #pragma unroll
    for (int j = 0; j < 8; ++j) atomicAdd(&out[j], w * v[j]);
}

// ---------------- GEMM1: h1 = relu(z1 @ W1^T + b1), bf16 in-place --------------
__global__ __launch_bounds__(256) void k_gemm1(
    float* buf, const void* __restrict__ W1, const void* __restrict__ b1,
    int N, const int* __restrict__ flag)
{
    int isbf = *flag;
    __shared__ int4 lds[2048];  // 8 nt * 4 kt * 64 lanes = 32KB, B-fragment order
    int tid = threadIdx.x;
    for (int u = tid; u < 2048; u += 256) {
        int nt = u >> 8, kt = (u >> 6) & 3, lane = u & 63;
        int so = (nt * 16 + (lane & 15)) * 128 + kt * 32 + ((lane >> 4) << 3);
        lds[u] = ld8frag(W1, so, isbf);
    }
    __syncthreads();

    int wave = tid >> 6, lane = tid & 63;
    int ntile = (N + 15) >> 4;
    int tile = blockIdx.x * 4 + wave;
    if (tile >= ntile) return;
    int m = lane & 15, quad = lane >> 4;

    int arow = tile * 16 + m;
    if (arow >= N) arow = N - 1;
    bf16x8 a[4];
    for (int kt = 0; kt < 4; ++kt) {
        const float* p = &buf[arow * 128 + kt * 32 + quad * 8];
        float4 f0 = *(const float4*)p;
        float4 f1 = *(const float4*)(p + 4);
        ushort8 t;
        t[0]=f2bf(f0.x); t[1]=f2bf(f0.y); t[2]=f2bf(f0.z); t[3]=f2bf(f0.w);
        t[4]=f2bf(f1.x); t[5]=f2bf(f1.y); t[6]=f2bf(f1.z); t[7]=f2bf(f1.w);
        a[kt] = __builtin_bit_cast(bf16x8, t);
    }

    floatx4 acc[8];
    floatx4 z = {0.f, 0.f, 0.f, 0.f};
    for (int nt = 0; nt < 8; ++nt) acc[nt] = z;
    for (int kt = 0; kt < 4; ++kt)
        for (int nt = 0; nt < 8; ++nt) {
            bf16x8 b = __builtin_bit_cast(bf16x8, lds[nt * 256 + kt * 64 + lane]);
            acc[nt] = __builtin_amdgcn_mfma_f32_16x16x32_bf16(a[kt], b, acc[nt], 0, 0, 0);
        }

    // C/D layout: col = lane&15, row = quad*4 + reg
    unsigned short* h1 = (unsigned short*)buf;   // stride 256 shorts/row
    int rbase = tile * 16 + quad * 4;
    for (int nt = 0; nt < 8; ++nt) {
        int col = nt * 16 + m;
        float bb = bread(b1, col, isbf);
        for (int r = 0; r < 4; ++r) {
            int orow = rbase + r;
            if (orow < N) {
                float v = acc[nt][r] + bb;
                h1[orow * 256 + col] = f2bf(fmaxf(v, 0.f));
            }
        }
    }
}

// ---------------- GEMM2: h2 = h1 @ W2^T; in-place h2 bf16 + agg2 f32 -----------
__global__ __launch_bounds__(256) void k_gemm2(
    float* buf, const void* __restrict__ W2, const void* __restrict__ b2,
    const float* __restrict__ dinv, int N, const int* __restrict__ flag)
{
    int isbf = *flag;
    __shared__ int4 lds[1024];  // 4 nt * 4 kt * 64 lanes = 16KB
    int tid = threadIdx.x;
    for (int u = tid; u < 1024; u += 256) {
        int nt = u >> 8, kt = (u >> 6) & 3, lane = u & 63;
        int so = (nt * 16 + (lane & 15)) * 128 + kt * 32 + ((lane >> 4) << 3);
        lds[u] = ld8frag(W2, so, isbf);
    }
    __syncthreads();

    int wave = tid >> 6, lane = tid & 63;
    int ntile = (N + 15) >> 4;
    int tile = blockIdx.x * 4 + wave;
    if (tile >= ntile) return;
    int m = lane & 15, quad = lane >> 4;

    const unsigned short* h1 = (const unsigned short*)buf;  // stride 256
    int arow = tile * 16 + m;
    if (arow >= N) arow = N - 1;
    bf16x8 a[4];
    for (int kt = 0; kt < 4; ++kt)
        a[kt] = __builtin_bit_cast(bf16x8, *(const int4*)&h1[arow * 256 + kt * 32 + quad * 8]);

    floatx4 acc[4];
    floatx4 z = {0.f, 0.f, 0.f, 0.f};
    for (int nt = 0; nt < 4; ++nt) acc[nt] = z;
    for (int kt = 0; kt < 4; ++kt)
        for (int nt = 0; nt < 4; ++nt) {
            bf16x8 b = __builtin_bit_cast(bf16x8, lds[nt * 256 + kt * 64 + lane]);
            acc[nt] = __builtin_amdgcn_mfma_f32_16x16x32_bf16(a[kt], b, acc[nt], 0, 0, 0);
        }

    unsigned short* h2 = (unsigned short*)buf;  // stride 256 shorts, entries [0,64)
    int rbase = tile * 16 + quad * 4;
    float di[4];
    for (int r = 0; r < 4; ++r) {
        int orow = rbase + r;
        di[r] = (orow < N) ? dinv[orow] : 0.f;
    }
    for (int nt = 0; nt < 4; ++nt) {
        int col = nt * 16 + m;
        float bb = bread(b2, col, isbf);
        for (int r = 0; r < 4; ++r) {
            int orow = rbase + r;
            if (orow < N) {
                float v = acc[nt][r];
                h2[orow * 256 + col] = f2bf(v);
                buf[orow * 128 + 64 + col] = bb + di[r] * di[r] * v;  // agg2
            }
        }
    }
}

// ---------------- edge agg layer2: agg2[d,:] += w * h2[s,:] (64 feats) ---------
__global__ __launch_bounds__(256) void k_aggh2(
    const int* __restrict__ src, const int* __restrict__ dst,
    const float* __restrict__ dinv, float* buf, int E)
{
    int gid = blockIdx.x * 256 + threadIdx.x;
    int e = gid >> 3, p = gid & 7;
    if (e >= E) return;
    int s = src[e], d = dst[e];
    float w = dinv[s] * dinv[d];
    const unsigned short* h2 = (const unsigned short*)buf;
    ushort8 hv = __builtin_bit_cast(ushort8, *(const int4*)&h2[s * 256 + p * 8]);
    float* out = &buf[d * 128 + 64 + p * 8];
    #pragma unroll
    for (int j = 0; j < 8; ++j) atomicAdd(&out[j], w * bf2f(hv[j]));
}

// ---------------- final cast/store ----------------
__global__ void k_out(const float* __restrict__ buf, void* __restrict__ out, int N,
                      const int* __restrict__ flag) {
    int isbf = *flag;
    int i = blockIdx.x * 256 + threadIdx.x;   // N*16 threads, one float4 each
    if (i >= N * 16) return;
    int row = i >> 4, j = i & 15;
    float4 v = *(const float4*)&buf[row * 128 + 64 + j * 4];
    if (isbf) {
        ushort4 o;
        o.x = f2bf(v.x); o.y = f2bf(v.y); o.z = f2bf(v.z); o.w = f2bf(v.w);
        *(ushort4*)((unsigned short*)out + row * 64 + j * 4) = o;
    } else {
        *(float4*)((float*)out + row * 64 + j * 4) = v;
    }
}

extern "C" void kernel_launch(void* const* d_in, const int* in_sizes, int n_in,
                              void* d_out, int out_size, void* d_ws, size_t ws_size,
                              hipStream_t stream) {
    const void* x  = d_in[0];
    const int*  ei = (const int*)d_in[1];
    const void* W1 = d_in[2];
    const void* b1 = d_in[3];
    const void* W2 = d_in[4];
    const void* b2 = d_in[5];

    int N = in_sizes[0] / 128;
    int E = in_sizes[1] / 2;
    const int* srcI = ei;
    const int* dstI = ei + E;

    // ws: flag @0 (256B slot), dinv f32[N], row arena N x 512B. ~25.9 MB.
    char* base = (char*)d_ws;
    int* flag = (int*)base;
    float* dinv = (float*)(base + 256);
    size_t arena_off = 256 + (((size_t)N * 4 + 255) & ~(size_t)255);
    float* buf = (float*)(base + arena_off);

    int ntile = (N + 15) / 16;
    int gemmBlocks = (ntile + 3) / 4;

    k_detect<<<1, 256, 0, stream>>>((const unsigned*)x, flag);
    k_fill1<<<(N + 255) / 256, 256, 0, stream>>>(dinv, N);
    k_deg<<<(E + 255) / 256, 256, 0, stream>>>(dstI, dinv, E);
    k_rsqrt<<<(N + 255) / 256, 256, 0, stream>>>(dinv, N);
    k_selfx<<<(N * 16 + 255) / 256, 256, 0, stream>>>(x, dinv, buf, N, flag);
    k_aggx<<<(int)(((long long)E * 16 + 255) / 256), 256, 0, stream>>>(srcI, dstI, dinv, x, buf, E, flag);
    k_gemm1<<<gemmBlocks, 256, 0, stream>>>(buf, W1, b1, N, flag);
    k_gemm2<<<gemmBlocks, 256, 0, stream>>>(buf, W2, b2, dinv, N, flag);
    k_aggh2<<<(int)(((long long)E * 8 + 255) / 256), 256, 0, stream>>>(srcI, dstI, dinv, buf, E);
    k_out<<<(N * 16 + 255) / 256, 256, 0, stream>>>(buf, d_out, N, flag);
}

// Round 5
// 298.097 us; speedup vs baseline: 11.5289x; 11.5289x over previous
//
#include <hip/hip_runtime.h>
#include <hip/hip_bf16.h>

// GCN 2-layer, N=50000, E=625000, feats 128->128->64. int32 edges.
// Round 5: replace feature-atomic aggregation (2.5 GB fabric atomics, 2.2ms+1.1ms)
// with CSR-by-dst gather (register accumulation, one write per row).
// Dtype of float tensors runtime-detected (bf16 vs f32), as in round 4 (passed).
// Workspace (~28.9 MB): flag | cnt int[N] | off int[N+1] | cursor int[N] |
//   dinv f32[N] | bucket int[E] | row arena N x 512B:
//     phase1: z1 f32[128]            (bytes 0..512)
//     gemm1 : h1 bf16[128] in-place  (bytes 0..256)   -- rows wave-private
//     gemm2 : h2 bf16[64]  in-place  (bytes 0..128)
// Layer1 aggregate-first (linearity), Layer2 GEMM-first (64-wide gather).

typedef __attribute__((ext_vector_type(8))) __bf16 bf16x8;
typedef __attribute__((ext_vector_type(8))) unsigned short ushort8;
typedef __attribute__((ext_vector_type(4))) float floatx4;

static __device__ __forceinline__ float bf2f(unsigned short s) {
    unsigned u = ((unsigned)s) << 16;
    return __builtin_bit_cast(float, u);
}
static __device__ __forceinline__ unsigned short f2bf(float f) {
    unsigned u = __builtin_bit_cast(unsigned, f);
    unsigned r = (u + 0x7FFFu + ((u >> 16) & 1u)) >> 16;
    return (unsigned short)r;
}
// load 8 consecutive feature elements (idx in elements) as f32[8]
static __device__ __forceinline__ void ld8f(const void* p, size_t idx, int isbf, float* o) {
    if (isbf) {
        ushort8 t = __builtin_bit_cast(ushort8, *(const int4*)((const unsigned short*)p + idx));
        #pragma unroll
        for (int j = 0; j < 8; ++j) o[j] = bf2f(t[j]);
    } else {
        const float* f = (const float*)p + idx;
        float4 a = *(const float4*)f;
        float4 b = *(const float4*)(f + 4);
        o[0]=a.x; o[1]=a.y; o[2]=a.z; o[3]=a.w; o[4]=b.x; o[5]=b.y; o[6]=b.z; o[7]=b.w;
    }
}
// load 8 consecutive elements as a bf16x8 MFMA fragment
static __device__ __forceinline__ int4 ld8frag(const void* p, size_t idx, int isbf) {
    if (isbf) {
        return *(const int4*)((const unsigned short*)p + idx);
    } else {
        const float* f = (const float*)p + idx;
        float4 a = *(const float4*)f;
        float4 b = *(const float4*)(f + 4);
        ushort8 t;
        t[0]=f2bf(a.x); t[1]=f2bf(a.y); t[2]=f2bf(a.z); t[3]=f2bf(a.w);
        t[4]=f2bf(b.x); t[5]=f2bf(b.y); t[6]=f2bf(b.z); t[7]=f2bf(b.w);
        return __builtin_bit_cast(int4, t);
    }
}
static __device__ __forceinline__ float bread(const void* p, int i, int isbf) {
    return isbf ? bf2f(((const unsigned short*)p)[i]) : ((const float*)p)[i];
}

// ---------------- dtype detect: bf16 iff low halves of x words are sane bf16 ----
__global__ void k_detect(const unsigned* __restrict__ xw, int* flag) {
    __shared__ int red[256];
    int t = threadIdx.x;
    int cnt = 0;
    #pragma unroll
    for (int i = 0; i < 16; ++i) {
        unsigned w = xw[t * 16 + i];
        unsigned exp = (w >> 7) & 0xFFu;     // exponent of low-half bf16
        cnt += (exp <= 0x84u) ? 1 : 0;       // |v| < 64
    }
    red[t] = cnt;
    __syncthreads();
    for (int s = 128; s > 0; s >>= 1) {
        if (t < s) red[t] += red[t + s];
        __syncthreads();
    }
    if (t == 0) flag[0] = (red[0] >= 3686) ? 1 : 0;   // >=90% of 4096
}

// ---------------- CSR build ----------------
__global__ void k_zero(int* cnt, int n) {
    int i = blockIdx.x * 256 + threadIdx.x;
    if (i < n) cnt[i] = 0;
}
__global__ void k_count(const int* __restrict__ dst, int* __restrict__ cnt, int E) {
    int e = blockIdx.x * 256 + threadIdx.x;
    if (e < E) atomicAdd(&cnt[dst[e]], 1);
}
// exclusive scan of cnt -> off[0..N], cursor copy, dinv = rsqrt(1+cnt)
__global__ __launch_bounds__(1024) void k_scan(
    const int* __restrict__ cnt, int* __restrict__ off, int* __restrict__ cursor,
    float* __restrict__ dinv, int N)
{
    __shared__ int wtot[16];
    __shared__ int woff[16];
    __shared__ int s_carry;
    int t = threadIdx.x, lane = t & 63, wid = t >> 6;
    if (t == 0) s_carry = 0;
    __syncthreads();
    int nchunk = (N + 1023) / 1024;
    for (int c = 0; c < nchunk; ++c) {
        int i = c * 1024 + t;
        int v = (i < N) ? cnt[i] : 0;
        int x = v;
        #pragma unroll
        for (int s = 1; s < 64; s <<= 1) {
            int u = __shfl_up(x, s, 64);
            if (lane >= s) x += u;
        }
        if (lane == 63) wtot[wid] = x;
        __syncthreads();
        if (wid == 0) {
            int tv = (lane < 16) ? wtot[lane] : 0;
            int y = tv;
            #pragma unroll
            for (int s = 1; s < 16; s <<= 1) {
                int u = __shfl_up(y, s, 64);
                if (lane >= s) y += u;
            }
            if (lane < 16) woff[lane] = y - tv;   // exclusive wave offset
        }
        __syncthreads();
        int carry = s_carry;
        if (i < N) {
            int excl = carry + woff[wid] + (x - v);
            off[i] = excl;
            cursor[i] = excl;
            dinv[i] = rsqrtf(1.0f + (float)v);
        }
        __syncthreads();   // all reads of s_carry/woff done
        if (t == 0) s_carry = carry + woff[15] + wtot[15];
        __syncthreads();   // also protects wtot before next-chunk overwrite
    }
    if (t == 0) off[N] = s_carry;
}
__global__ void k_scatter(const int* __restrict__ src, const int* __restrict__ dst,
                          int* __restrict__ cursor, int* __restrict__ bucket, int E) {
    int e = blockIdx.x * 256 + threadIdx.x;
    if (e >= E) return;
    int pos = atomicAdd(&cursor[dst[e]], 1);
    bucket[pos] = src[e];
}

// ---------------- gather layer1: z1[d,:] = dinv_d*(dinv_d*x[d] + sum w*x[s]) ----
// 16 lanes per node, 16 nodes per 256-block. Register accumulation, one write.
__global__ __launch_bounds__(256) void k_gather1(
    const void* __restrict__ x, const float* __restrict__ dinv,
    const int* __restrict__ off, const int* __restrict__ bucket,
    float* __restrict__ buf, int N, const int* __restrict__ flag)
{
    int isbf = *flag;
    int gid = blockIdx.x * 256 + threadIdx.x;
    int node = gid >> 4, p = gid & 15;
    if (node >= N) return;
    float di = dinv[node];
    float acc[8], v[8];
    ld8f(x, (size_t)node * 128 + p * 8, isbf, v);        // self term
    float w0 = di * di;
    #pragma unroll
    for (int j = 0; j < 8; ++j) acc[j] = w0 * v[j];
    int s0 = off[node], s1 = off[node + 1];
    for (int it = s0; it < s1; ++it) {
        int s = bucket[it];
        float w = di * dinv[s];
        ld8f(x, (size_t)s * 128 + p * 8, isbf, v);
        #pragma unroll
        for (int j = 0; j < 8; ++j) acc[j] += w * v[j];
    }
    float* o = &buf[(size_t)node * 128 + p * 8];
    float4 a = {acc[0], acc[1], acc[2], acc[3]};
    float4 b = {acc[4], acc[5], acc[6], acc[7]};
    *(float4*)o = a;
    *(float4*)(o + 4) = b;
}

// ---------------- GEMM1: h1 = relu(z1 @ W1^T + b1), bf16 in-place --------------
__global__ __launch_bounds__(256) void k_gemm1(
    float* buf, const void* __restrict__ W1, const void* __restrict__ b1,
    int N, const int* __restrict__ flag)
{
    int isbf = *flag;
    __shared__ int4 lds[2048];  // 8 nt * 4 kt * 64 lanes = 32KB, B-fragment order
    int tid = threadIdx.x;
    for (int u = tid; u < 2048; u += 256) {
        int nt = u >> 8, kt = (u >> 6) & 3, lane = u & 63;
        int so = (nt * 16 + (lane & 15)) * 128 + kt * 32 + ((lane >> 4) << 3);
        lds[u] = ld8frag(W1, so, isbf);
    }
    __syncthreads();

    int wave = tid >> 6, lane = tid & 63;
    int ntile = (N + 15) >> 4;
    int tile = blockIdx.x * 4 + wave;
    if (tile >= ntile) return;
    int m = lane & 15, quad = lane >> 4;

    int arow = tile * 16 + m;
    if (arow >= N) arow = N - 1;
    bf16x8 a[4];
    for (int kt = 0; kt < 4; ++kt) {
        const float* p = &buf[(size_t)arow * 128 + kt * 32 + quad * 8];
        float4 f0 = *(const float4*)p;
        float4 f1 = *(const float4*)(p + 4);
        ushort8 t;
        t[0]=f2bf(f0.x); t[1]=f2bf(f0.y); t[2]=f2bf(f0.z); t[3]=f2bf(f0.w);
        t[4]=f2bf(f1.x); t[5]=f2bf(f1.y); t[6]=f2bf(f1.z); t[7]=f2bf(f1.w);
        a[kt] = __builtin_bit_cast(bf16x8, t);
    }

    floatx4 acc[8];
    floatx4 z = {0.f, 0.f, 0.f, 0.f};
    for (int nt = 0; nt < 8; ++nt) acc[nt] = z;
    for (int kt = 0; kt < 4; ++kt)
        for (int nt = 0; nt < 8; ++nt) {
            bf16x8 b = __builtin_bit_cast(bf16x8, lds[nt * 256 + kt * 64 + lane]);
            acc[nt] = __builtin_amdgcn_mfma_f32_16x16x32_bf16(a[kt], b, acc[nt], 0, 0, 0);
        }

    // C/D layout: col = lane&15, row = quad*4 + reg
    unsigned short* h1 = (unsigned short*)buf;   // stride 256 shorts/row
    int rbase = tile * 16 + quad * 4;
    for (int nt = 0; nt < 8; ++nt) {
        int col = nt * 16 + m;
        float bb = bread(b1, col, isbf);
        for (int r = 0; r < 4; ++r) {
            int orow = rbase + r;
            if (orow < N) {
                float v = acc[nt][r] + bb;
                h1[(size_t)orow * 256 + col] = f2bf(fmaxf(v, 0.f));
            }
        }
    }
}

// ---------------- GEMM2: h2 = h1 @ W2^T, bf16 in-place (no bias/self here) -----
__global__ __launch_bounds__(256) void k_gemm2(
    float* buf, const void* __restrict__ W2, int N, const int* __restrict__ flag)
{
    int isbf = *flag;
    __shared__ int4 lds[1024];  // 4 nt * 4 kt * 64 lanes = 16KB
    int tid = threadIdx.x;
    for (int u = tid; u < 1024; u += 256) {
        int nt = u >> 8, kt = (u >> 6) & 3, lane = u & 63;
        int so = (nt * 16 + (lane & 15)) * 128 + kt * 32 + ((lane >> 4) << 3);
        lds[u] = ld8frag(W2, so, isbf);
    }
    __syncthreads();

    int wave = tid >> 6, lane = tid & 63;
    int ntile = (N + 15) >> 4;
    int tile = blockIdx.x * 4 + wave;
    if (tile >= ntile) return;
    int m = lane & 15, quad = lane >> 4;

    const unsigned short* h1 = (const unsigned short*)buf;  // stride 256
    int arow = tile * 16 + m;
    if (arow >= N) arow = N - 1;
    bf16x8 a[4];
    for (int kt = 0; kt < 4; ++kt)
        a[kt] = __builtin_bit_cast(bf16x8, *(const int4*)&h1[(size_t)arow * 256 + kt * 32 + quad * 8]);

    floatx4 acc[4];
    floatx4 z = {0.f, 0.f, 0.f, 0.f};
    for (int nt = 0; nt < 4; ++nt) acc[nt] = z;
    for (int kt = 0; kt < 4; ++kt)
        for (int nt = 0; nt < 4; ++nt) {
            bf16x8 b = __builtin_bit_cast(bf16x8, lds[nt * 256 + kt * 64 + lane]);
            acc[nt] = __builtin_amdgcn_mfma_f32_16x16x32_bf16(a[kt], b, acc[nt], 0, 0, 0);
        }

    unsigned short* h2 = (unsigned short*)buf;  // stride 256 shorts, entries [0,64)
    int rbase = tile * 16 + quad * 4;
    for (int nt = 0; nt < 4; ++nt) {
        int col = nt * 16 + m;
        for (int r = 0; r < 4; ++r) {
            int orow = rbase + r;
            if (orow < N)
                h2[(size_t)orow * 256 + col] = f2bf(acc[nt][r]);
        }
    }
}

// ---------------- gather layer2: out[d,:] = b2 + dinv_d*(dinv_d*h2[d] + sum w*h2[s])
// 8 lanes per node, 32 nodes per 256-block. Fused bias + self + output store.
__global__ __launch_bounds__(256) void k_gather2(
    const float* __restrict__ buf, const float* __restrict__ dinv,
    const int* __restrict__ off, const int* __restrict__ bucket,
    const void* __restrict__ b2, void* __restrict__ out, int N,
    const int* __restrict__ flag)
{
    int isbf = *flag;
    int gid = blockIdx.x * 256 + threadIdx.x;
    int node = gid >> 3, p = gid & 7;
    if (node >= N) return;
    const unsigned short* h2 = (const unsigned short*)buf;  // stride 256, [0,64)
    float di = dinv[node];
    float acc[8];
    {
        ushort8 t = __builtin_bit_cast(ushort8, *(const int4*)&h2[(size_t)node * 256 + p * 8]);
        float w0 = di * di;
        #pragma unroll
        for (int j = 0; j < 8; ++j) acc[j] = w0 * bf2f(t[j]);
    }
    int s0 = off[node], s1 = off[node + 1];
    for (int it = s0; it < s1; ++it) {
        int s = bucket[it];
        float w = di * dinv[s];
        ushort8 t = __builtin_bit_cast(ushort8, *(const int4*)&h2[(size_t)s * 256 + p * 8]);
        #pragma unroll
        for (int j = 0; j < 8; ++j) acc[j] += w * bf2f(t[j]);
    }
    #pragma unroll
    for (int j = 0; j < 8; ++j) acc[j] += bread(b2, p * 8 + j, isbf);
    if (isbf) {
        ushort8 o;
        #pragma unroll
        for (int j = 0; j < 8; ++j) o[j] = f2bf(acc[j]);
        *(int4*)((unsigned short*)out + (size_t)node * 64 + p * 8) = __builtin_bit_cast(int4, o);
    } else {
        float* fo = (float*)out + (size_t)node * 64 + p * 8;
        float4 a = {acc[0], acc[1], acc[2], acc[3]};
        float4 b = {acc[4], acc[5], acc[6], acc[7]};
        *(float4*)fo = a;
        *(float4*)(fo + 4) = b;
    }
}

extern "C" void kernel_launch(void* const* d_in, const int* in_sizes, int n_in,
                              void* d_out, int out_size, void* d_ws, size_t ws_size,
                              hipStream_t stream) {
    const void* x  = d_in[0];
    const int*  ei = (const int*)d_in[1];
    const void* W1 = d_in[2];
    const void* b1 = d_in[3];
    const void* W2 = d_in[4];
    const void* b2 = d_in[5];

    int N = in_sizes[0] / 128;
    int E = in_sizes[1] / 2;
    const int* srcI = ei;
    const int* dstI = ei + E;

    // ws layout (256B-aligned chunks), ~28.9 MB total
    char* base = (char*)d_ws;
    size_t o = 0;
    auto take = [&](size_t bytes) { size_t r = o; o += (bytes + 255) & ~(size_t)255; return r; };
    int*   flag   = (int*)  (base + take(4));
    int*   cnt    = (int*)  (base + take((size_t)N * 4));
    int*   off    = (int*)  (base + take((size_t)(N + 1) * 4));
    int*   cursor = (int*)  (base + take((size_t)N * 4));
    float* dinv   = (float*)(base + take((size_t)N * 4));
    int*   bucket = (int*)  (base + take((size_t)E * 4));
    float* buf    = (float*)(base + take((size_t)N * 512));

    int ntile = (N + 15) / 16;
    int gemmBlocks = (ntile + 3) / 4;

    k_detect<<<1, 256, 0, stream>>>((const unsigned*)x, flag);
    k_zero<<<(N + 255) / 256, 256, 0, stream>>>(cnt, N);
    k_count<<<(E + 255) / 256, 256, 0, stream>>>(dstI, cnt, E);
    k_scan<<<1, 1024, 0, stream>>>(cnt, off, cursor, dinv, N);
    k_scatter<<<(E + 255) / 256, 256, 0, stream>>>(srcI, dstI, cursor, bucket, E);
    k_gather1<<<(N * 16 + 255) / 256, 256, 0, stream>>>(x, dinv, off, bucket, buf, N, flag);
    k_gemm1<<<gemmBlocks, 256, 0, stream>>>(buf, W1, b1, N, flag);
    k_gemm2<<<gemmBlocks, 256, 0, stream>>>(buf, W2, N, flag);
    k_gather2<<<(N * 8 + 255) / 256, 256, 0, stream>>>(buf, dinv, off, bucket, b2, d_out, N, flag);
}

// Round 6
// 246.616 us; speedup vs baseline: 13.9356x; 1.2088x over previous
//
#include <hip/hip_runtime.h>
#include <hip/hip_bf16.h>

// GCN 2-layer, N=50000, E=625000, feats 128->128->64. int32 edges.
// Round 6: parallelize the CSR prefix scan (was 53us single-block = 18% of wall)
// into 3 small dispatches; 2x-unroll gather loops for memory-level parallelism.
// Dtype of float tensors runtime-detected (bf16 vs f32) as in rounds 4-5 (passed).
// Workspace (~28.9 MB): flag | cnt | off | cursor | dinv | partial | prefix |
//   bucket int[E] | row arena N x 512B:
//     phase1: z1 f32[128]            (bytes 0..512)
//     gemm1 : h1 bf16[128] in-place  (bytes 0..256)   -- rows wave-private
//     gemm2 : h2 bf16[64]  in-place  (bytes 0..128)
// Layer1 aggregate-first (linearity), Layer2 GEMM-first (64-wide gather).

typedef __attribute__((ext_vector_type(8))) __bf16 bf16x8;
typedef __attribute__((ext_vector_type(8))) unsigned short ushort8;
typedef __attribute__((ext_vector_type(4))) float floatx4;

static __device__ __forceinline__ float bf2f(unsigned short s) {
    unsigned u = ((unsigned)s) << 16;
    return __builtin_bit_cast(float, u);
}
static __device__ __forceinline__ unsigned short f2bf(float f) {
    unsigned u = __builtin_bit_cast(unsigned, f);
    unsigned r = (u + 0x7FFFu + ((u >> 16) & 1u)) >> 16;
    return (unsigned short)r;
}
// load 8 consecutive feature elements (idx in elements) as f32[8]
static __device__ __forceinline__ void ld8f(const void* p, size_t idx, int isbf, float* o) {
    if (isbf) {
        ushort8 t = __builtin_bit_cast(ushort8, *(const int4*)((const unsigned short*)p + idx));
        #pragma unroll
        for (int j = 0; j < 8; ++j) o[j] = bf2f(t[j]);
    } else {
        const float* f = (const float*)p + idx;
        float4 a = *(const float4*)f;
        float4 b = *(const float4*)(f + 4);
        o[0]=a.x; o[1]=a.y; o[2]=a.z; o[3]=a.w; o[4]=b.x; o[5]=b.y; o[6]=b.z; o[7]=b.w;
    }
}
// load 8 consecutive elements as a bf16x8 MFMA fragment
static __device__ __forceinline__ int4 ld8frag(const void* p, size_t idx, int isbf) {
    if (isbf) {
        return *(const int4*)((const unsigned short*)p + idx);
    } else {
        const float* f = (const float*)p + idx;
        float4 a = *(const float4*)f;
        float4 b = *(const float4*)(f + 4);
        ushort8 t;
        t[0]=f2bf(a.x); t[1]=f2bf(a.y); t[2]=f2bf(a.z); t[3]=f2bf(a.w);
        t[4]=f2bf(b.x); t[5]=f2bf(b.y); t[6]=f2bf(b.z); t[7]=f2bf(b.w);
        return __builtin_bit_cast(int4, t);
    }
}
static __device__ __forceinline__ float bread(const void* p, int i, int isbf) {
    return isbf ? bf2f(((const unsigned short*)p)[i]) : ((const float*)p)[i];
}

// ---------------- dtype detect: bf16 iff low halves of x words are sane bf16 ----
__global__ void k_detect(const unsigned* __restrict__ xw, int* flag) {
    __shared__ int red[256];
    int t = threadIdx.x;
    int cnt = 0;
    #pragma unroll
    for (int i = 0; i < 16; ++i) {
        unsigned w = xw[t * 16 + i];
        unsigned exp = (w >> 7) & 0xFFu;     // exponent of low-half bf16
        cnt += (exp <= 0x84u) ? 1 : 0;       // |v| < 64
    }
    red[t] = cnt;
    __syncthreads();
    for (int s = 128; s > 0; s >>= 1) {
        if (t < s) red[t] += red[t + s];
        __syncthreads();
    }
    if (t == 0) flag[0] = (red[0] >= 3686) ? 1 : 0;   // >=90% of 4096
}

// ---------------- CSR build ----------------
__global__ void k_zero(int* cnt, int n) {
    int i = blockIdx.x * 256 + threadIdx.x;
    if (i < n) cnt[i] = 0;
}
__global__ void k_count(const int* __restrict__ dst, int* __restrict__ cnt, int E) {
    int e = blockIdx.x * 256 + threadIdx.x;
    if (e < E) atomicAdd(&cnt[dst[e]], 1);
}

// parallel scan, 1024 items/block: A = block sums, B = scan of partials, C = emit
__global__ __launch_bounds__(256) void k_scanA(
    const int* __restrict__ cnt, int* __restrict__ partial, int N)
{
    int b = blockIdx.x, t = threadIdx.x;
    int base = b * 1024 + t * 4;
    int s = 0;
    if (base + 3 < N) {
        int4 v = *(const int4*)&cnt[base];
        s = v.x + v.y + v.z + v.w;
    } else {
        for (int j = 0; j < 4; ++j) { int i = base + j; if (i < N) s += cnt[i]; }
    }
    #pragma unroll
    for (int d = 1; d < 64; d <<= 1) s += __shfl_down(s, d, 64);
    __shared__ int ws[4];
    int lane = t & 63, wid = t >> 6;
    if (lane == 0) ws[wid] = s;
    __syncthreads();
    if (t == 0) partial[b] = ws[0] + ws[1] + ws[2] + ws[3];
}
__global__ void k_scanB(const int* __restrict__ partial, int* __restrict__ prefix, int nb) {
    int lane = threadIdx.x;   // one wave (64)
    int carry = 0;
    int nch = (nb + 63) / 64;
    for (int c = 0; c < nch; ++c) {
        int i = c * 64 + lane;
        int v = (i < nb) ? partial[i] : 0;
        int x = v;
        #pragma unroll
        for (int d = 1; d < 64; d <<= 1) {
            int u = __shfl_up(x, d, 64);
            if (lane >= d) x += u;
        }
        if (i < nb) prefix[i] = carry + x - v;
        carry += __shfl(x, 63, 64);
    }
    if (lane == 0) prefix[nb] = carry;
}
__global__ __launch_bounds__(256) void k_scanC(
    const int* __restrict__ cnt, const int* __restrict__ prefix,
    int* __restrict__ off, int* __restrict__ cursor, float* __restrict__ dinv,
    int N, int nb)
{
    int b = blockIdx.x, t = threadIdx.x, lane = t & 63, wid = t >> 6;
    int base = b * 1024 + t * 4;
    int v[4], s = 0;
    #pragma unroll
    for (int j = 0; j < 4; ++j) {
        int i = base + j;
        v[j] = (i < N) ? cnt[i] : 0;
        s += v[j];
    }
    int x = s;
    #pragma unroll
    for (int d = 1; d < 64; d <<= 1) {
        int u = __shfl_up(x, d, 64);
        if (lane >= d) x += u;
    }
    __shared__ int wtot[4], woff[4];
    if (lane == 63) wtot[wid] = x;
    __syncthreads();
    if (t == 0) {
        int a = 0;
        #pragma unroll
        for (int w = 0; w < 4; ++w) { woff[w] = a; a += wtot[w]; }
    }
    __syncthreads();
    int excl = prefix[b] + woff[wid] + (x - s);
    #pragma unroll
    for (int j = 0; j < 4; ++j) {
        int i = base + j;
        if (i < N) {
            off[i] = excl;
            cursor[i] = excl;
            dinv[i] = rsqrtf(1.0f + (float)v[j]);
            excl += v[j];
        }
    }
    if (b == 0 && t == 0) off[N] = prefix[nb];
}

__global__ void k_scatter(const int* __restrict__ src, const int* __restrict__ dst,
                          int* __restrict__ cursor, int* __restrict__ bucket, int E) {
    int e = blockIdx.x * 256 + threadIdx.x;
    if (e >= E) return;
    int pos = atomicAdd(&cursor[dst[e]], 1);
    bucket[pos] = src[e];
}

// ---------------- gather layer1: z1[d,:] = dinv_d*(dinv_d*x[d] + sum w*x[s]) ----
// 16 lanes per node; register accumulation; 2x edge unroll for MLP.
__global__ __launch_bounds__(256) void k_gather1(
    const void* __restrict__ x, const float* __restrict__ dinv,
    const int* __restrict__ off, const int* __restrict__ bucket,
    float* __restrict__ buf, int N, const int* __restrict__ flag)
{
    int isbf = *flag;
    int gid = blockIdx.x * 256 + threadIdx.x;
    int node = gid >> 4, p = gid & 15;
    if (node >= N) return;
    float di = dinv[node];
    float acc[8], va[8], vb[8];
    ld8f(x, (size_t)node * 128 + p * 8, isbf, va);       // self term
    float w0 = di * di;
    #pragma unroll
    for (int j = 0; j < 8; ++j) acc[j] = w0 * va[j];
    int it = off[node], s1 = off[node + 1];
    for (; it + 1 < s1; it += 2) {
        int sa = bucket[it], sb = bucket[it + 1];
        float wa = di * dinv[sa], wb = di * dinv[sb];
        ld8f(x, (size_t)sa * 128 + p * 8, isbf, va);
        ld8f(x, (size_t)sb * 128 + p * 8, isbf, vb);
        #pragma unroll
        for (int j = 0; j < 8; ++j) acc[j] += wa * va[j] + wb * vb[j];
    }
    if (it < s1) {
        int sa = bucket[it];
        float wa = di * dinv[sa];
        ld8f(x, (size_t)sa * 128 + p * 8, isbf, va);
        #pragma unroll
        for (int j = 0; j < 8; ++j) acc[j] += wa * va[j];
    }
    float* o = &buf[(size_t)node * 128 + p * 8];
    float4 a = {acc[0], acc[1], acc[2], acc[3]};
    float4 b = {acc[4], acc[5], acc[6], acc[7]};
    *(float4*)o = a;
    *(float4*)(o + 4) = b;
}

// ---------------- GEMM1: h1 = relu(z1 @ W1^T + b1), bf16 in-place --------------
__global__ __launch_bounds__(256) void k_gemm1(
    float* buf, const void* __restrict__ W1, const void* __restrict__ b1,
    int N, const int* __restrict__ flag)
{
    int isbf = *flag;
    __shared__ int4 lds[2048];  // 8 nt * 4 kt * 64 lanes = 32KB, B-fragment order
    int tid = threadIdx.x;
    for (int u = tid; u < 2048; u += 256) {
        int nt = u >> 8, kt = (u >> 6) & 3, lane = u & 63;
        int so = (nt * 16 + (lane & 15)) * 128 + kt * 32 + ((lane >> 4) << 3);
        lds[u] = ld8frag(W1, so, isbf);
    }
    __syncthreads();

    int wave = tid >> 6, lane = tid & 63;
    int ntile = (N + 15) >> 4;
    int tile = blockIdx.x * 4 + wave;
    if (tile >= ntile) return;
    int m = lane & 15, quad = lane >> 4;

    int arow = tile * 16 + m;
    if (arow >= N) arow = N - 1;
    bf16x8 a[4];
    for (int kt = 0; kt < 4; ++kt) {
        const float* p = &buf[(size_t)arow * 128 + kt * 32 + quad * 8];
        float4 f0 = *(const float4*)p;
        float4 f1 = *(const float4*)(p + 4);
        ushort8 t;
        t[0]=f2bf(f0.x); t[1]=f2bf(f0.y); t[2]=f2bf(f0.z); t[3]=f2bf(f0.w);
        t[4]=f2bf(f1.x); t[5]=f2bf(f1.y); t[6]=f2bf(f1.z); t[7]=f2bf(f1.w);
        a[kt] = __builtin_bit_cast(bf16x8, t);
    }

    floatx4 acc[8];
    floatx4 z = {0.f, 0.f, 0.f, 0.f};
    for (int nt = 0; nt < 8; ++nt) acc[nt] = z;
    for (int kt = 0; kt < 4; ++kt)
        for (int nt = 0; nt < 8; ++nt) {
            bf16x8 b = __builtin_bit_cast(bf16x8, lds[nt * 256 + kt * 64 + lane]);
            acc[nt] = __builtin_amdgcn_mfma_f32_16x16x32_bf16(a[kt], b, acc[nt], 0, 0, 0);
        }

    // C/D layout: col = lane&15, row = quad*4 + reg
    unsigned short* h1 = (unsigned short*)buf;   // stride 256 shorts/row
    int rbase = tile * 16 + quad * 4;
    for (int nt = 0; nt < 8; ++nt) {
        int col = nt * 16 + m;
        float bb = bread(b1, col, isbf);
        for (int r = 0; r < 4; ++r) {
            int orow = rbase + r;
            if (orow < N) {
                float v = acc[nt][r] + bb;
                h1[(size_t)orow * 256 + col] = f2bf(fmaxf(v, 0.f));
            }
        }
    }
}

// ---------------- GEMM2: h2 = h1 @ W2^T, bf16 in-place -------------------------
__global__ __launch_bounds__(256) void k_gemm2(
    float* buf, const void* __restrict__ W2, int N, const int* __restrict__ flag)
{
    int isbf = *flag;
    __shared__ int4 lds[1024];  // 4 nt * 4 kt * 64 lanes = 16KB
    int tid = threadIdx.x;
    for (int u = tid; u < 1024; u += 256) {
        int nt = u >> 8, kt = (u >> 6) & 3, lane = u & 63;
        int so = (nt * 16 + (lane & 15)) * 128 + kt * 32 + ((lane >> 4) << 3);
        lds[u] = ld8frag(W2, so, isbf);
    }
    __syncthreads();

    int wave = tid >> 6, lane = tid & 63;
    int ntile = (N + 15) >> 4;
    int tile = blockIdx.x * 4 + wave;
    if (tile >= ntile) return;
    int m = lane & 15, quad = lane >> 4;

    const unsigned short* h1 = (const unsigned short*)buf;  // stride 256
    int arow = tile * 16 + m;
    if (arow >= N) arow = N - 1;
    bf16x8 a[4];
    for (int kt = 0; kt < 4; ++kt)
        a[kt] = __builtin_bit_cast(bf16x8, *(const int4*)&h1[(size_t)arow * 256 + kt * 32 + quad * 8]);

    floatx4 acc[4];
    floatx4 z = {0.f, 0.f, 0.f, 0.f};
    for (int nt = 0; nt < 4; ++nt) acc[nt] = z;
    for (int kt = 0; kt < 4; ++kt)
        for (int nt = 0; nt < 4; ++nt) {
            bf16x8 b = __builtin_bit_cast(bf16x8, lds[nt * 256 + kt * 64 + lane]);
            acc[nt] = __builtin_amdgcn_mfma_f32_16x16x32_bf16(a[kt], b, acc[nt], 0, 0, 0);
        }

    unsigned short* h2 = (unsigned short*)buf;  // stride 256 shorts, entries [0,64)
    int rbase = tile * 16 + quad * 4;
    for (int nt = 0; nt < 4; ++nt) {
        int col = nt * 16 + m;
        for (int r = 0; r < 4; ++r) {
            int orow = rbase + r;
            if (orow < N)
                h2[(size_t)orow * 256 + col] = f2bf(acc[nt][r]);
        }
    }
}

// ---------------- gather layer2: out[d,:] = b2 + dinv_d*(dinv_d*h2[d] + sum w*h2[s])
// 8 lanes per node; 2x edge unroll; fused bias + self + output store.
__global__ __launch_bounds__(256) void k_gather2(
    const float* __restrict__ buf, const float* __restrict__ dinv,
    const int* __restrict__ off, const int* __restrict__ bucket,
    const void* __restrict__ b2, void* __restrict__ out, int N,
    const int* __restrict__ flag)
{
    int isbf = *flag;
    int gid = blockIdx.x * 256 + threadIdx.x;
    int node = gid >> 3, p = gid & 7;
    if (node >= N) return;
    const unsigned short* h2 = (const unsigned short*)buf;  // stride 256, [0,64)
    float di = dinv[node];
    float acc[8];
    {
        ushort8 t = __builtin_bit_cast(ushort8, *(const int4*)&h2[(size_t)node * 256 + p * 8]);
        float w0 = di * di;
        #pragma unroll
        for (int j = 0; j < 8; ++j) acc[j] = w0 * bf2f(t[j]);
    }
    int it = off[node], s1 = off[node + 1];
    for (; it + 1 < s1; it += 2) {
        int sa = bucket[it], sb = bucket[it + 1];
        float wa = di * dinv[sa], wb = di * dinv[sb];
        ushort8 ta = __builtin_bit_cast(ushort8, *(const int4*)&h2[(size_t)sa * 256 + p * 8]);
        ushort8 tb = __builtin_bit_cast(ushort8, *(const int4*)&h2[(size_t)sb * 256 + p * 8]);
        #pragma unroll
        for (int j = 0; j < 8; ++j) acc[j] += wa * bf2f(ta[j]) + wb * bf2f(tb[j]);
    }
    if (it < s1) {
        int sa = bucket[it];
        float wa = di * dinv[sa];
        ushort8 ta = __builtin_bit_cast(ushort8, *(const int4*)&h2[(size_t)sa * 256 + p * 8]);
        #pragma unroll
        for (int j = 0; j < 8; ++j) acc[j] += wa * bf2f(ta[j]);
    }
    #pragma unroll
    for (int j = 0; j < 8; ++j) acc[j] += bread(b2, p * 8 + j, isbf);
    if (isbf) {
        ushort8 o;
        #pragma unroll
        for (int j = 0; j < 8; ++j) o[j] = f2bf(acc[j]);
        *(int4*)((unsigned short*)out + (size_t)node * 64 + p * 8) = __builtin_bit_cast(int4, o);
    } else {
        float* fo = (float*)out + (size_t)node * 64 + p * 8;
        float4 a = {acc[0], acc[1], acc[2], acc[3]};
        float4 b = {acc[4], acc[5], acc[6], acc[7]};
        *(float4*)fo = a;
        *(float4*)(fo + 4) = b;
    }
}

extern "C" void kernel_launch(void* const* d_in, const int* in_sizes, int n_in,
                              void* d_out, int out_size, void* d_ws, size_t ws_size,
                              hipStream_t stream) {
    const void* x  = d_in[0];
    const int*  ei = (const int*)d_in[1];
    const void* W1 = d_in[2];
    const void* b1 = d_in[3];
    const void* W2 = d_in[4];
    const void* b2 = d_in[5];

    int N = in_sizes[0] / 128;
    int E = in_sizes[1] / 2;
    const int* srcI = ei;
    const int* dstI = ei + E;

    int nb = (N + 1023) / 1024;   // scan blocks (49 for N=50000)

    // ws layout (256B-aligned chunks), ~28.9 MB total
    char* base = (char*)d_ws;
    size_t o = 0;
    auto take = [&](size_t bytes) { size_t r = o; o += (bytes + 255) & ~(size_t)255; return r; };
    int*   flag    = (int*)  (base + take(4));
    int*   cnt     = (int*)  (base + take((size_t)N * 4));
    int*   off     = (int*)  (base + take((size_t)(N + 1) * 4));
    int*   cursor  = (int*)  (base + take((size_t)N * 4));
    float* dinv    = (float*)(base + take((size_t)N * 4));
    int*   partial = (int*)  (base + take((size_t)nb * 4));
    int*   prefix  = (int*)  (base + take((size_t)(nb + 1) * 4));
    int*   bucket  = (int*)  (base + take((size_t)E * 4));
    float* buf     = (float*)(base + take((size_t)N * 512));

    int ntile = (N + 15) / 16;
    int gemmBlocks = (ntile + 3) / 4;

    k_detect<<<1, 256, 0, stream>>>((const unsigned*)x, flag);
    k_zero<<<(N + 255) / 256, 256, 0, stream>>>(cnt, N);
    k_count<<<(E + 255) / 256, 256, 0, stream>>>(dstI, cnt, E);
    k_scanA<<<nb, 256, 0, stream>>>(cnt, partial, N);
    k_scanB<<<1, 64, 0, stream>>>(partial, prefix, nb);
    k_scanC<<<nb, 256, 0, stream>>>(cnt, prefix, off, cursor, dinv, N, nb);
    k_scatter<<<(E + 255) / 256, 256, 0, stream>>>(srcI, dstI, cursor, bucket, E);
    k_gather1<<<(N * 16 + 255) / 256, 256, 0, stream>>>(x, dinv, off, bucket, buf, N, flag);
    k_gemm1<<<gemmBlocks, 256, 0, stream>>>(buf, W1, b1, N, flag);
    k_gemm2<<<gemmBlocks, 256, 0, stream>>>(buf, W2, N, flag);
    k_gather2<<<(N * 8 + 255) / 256, 256, 0, stream>>>(buf, dinv, off, bucket, b2, d_out, N, flag);
}